// Round 3
// baseline (210.357 us; speedup 1.0000x reference)
//
#include <hip/hip_runtime.h>
#include <cstddef>
#include <cstdint>

// ---------------- problem constants ----------------
#define cB   512
#define cV   5023
#define cS   100
#define cE   50
#define cJ   5
#define cLD  17
#define cLF  68

#define cV3    15069       // V*3
#define cNPAD  15072       // 157*96 padded N (rows of BTn)
#define cKPAD  192         // K padded (100+50+36 -> 192)

#define OUT_V  ((size_t)cB * cV * 3)
#define OUT_L  ((size_t)cB * cLF * 3)

// ws layout (float offsets; bf16 buffers are ushort-packed, 2 per float)
#define WS_BTN   ((size_t)0)                            // 15072*192 ushort
#define WS_ATM   (WS_BTN + (size_t)cNPAD * 96)          // 512*192 ushort
#define WS_JS    (WS_ATM + (size_t)cB * 96)             // 2272 floats
#define WS_AREL  (WS_JS + 2272)                         // 512*60
#define WS_PF    (WS_AREL + (size_t)cB * 60)            // 512*36
#define WS_YROT  (WS_PF + (size_t)cB * 36)              // 512 ints

typedef __attribute__((ext_vector_type(8))) short short8;
typedef __attribute__((ext_vector_type(4))) float f32x4;

// fp32 -> bf16 round-to-nearest-even
__device__ __forceinline__ unsigned short f2bf(float x) {
  unsigned int u = __float_as_uint(x);
  u = (u + 0x7fffu + ((u >> 16) & 1u)) >> 16;
  return (unsigned short)u;
}

// ---------------- rodrigues (matches jax reference in fp32) ----------------
__device__ __forceinline__ void rodrigues9(float rx, float ry, float rz, float* R) {
  float a0 = rx + 1e-8f, a1 = ry + 1e-8f, a2 = rz + 1e-8f;
  float angle = sqrtf(a0 * a0 + a1 * a1 + a2 * a2);
  float inv = 1.0f / angle;
  float x = rx * inv, y = ry * inv, z = rz * inv;
  float s = sinf(angle), c = cosf(angle);
  float t = 1.0f - c;
  float xy = x * y, xz = x * z, yz = y * z;
  R[0] = 1.0f - t * (y * y + z * z);
  R[1] = -s * z + t * xy;
  R[2] =  s * y + t * xz;
  R[3] =  s * z + t * xy;
  R[4] = 1.0f - t * (x * x + z * z);
  R[5] = -s * x + t * yz;
  R[6] = -s * y + t * xz;
  R[7] =  s * x + t * yz;
  R[8] = 1.0f - t * (x * x + y * y);
}

// ---------------- k_js: JS[j,c,l] = sum_v Jreg[j,v]*shapedirs[v,c,l]; l==150 -> v_template ----
// 157 blocks x 32 v, unroll 8 so loads pipeline (R2 was 40-deep serial dependent loads).
__global__ void k_js(const float* __restrict__ jreg, const float* __restrict__ sd,
                     const float* __restrict__ vt, float* __restrict__ JS) {
  int t = threadIdx.x;
  if (t >= 453) return;
  int c = t / 151, l = t - c * 151;
  int v0 = blockIdx.x * 32;
  int v1 = v0 + 32; if (v1 > cV) v1 = cV;
  float acc[5] = {0.f, 0.f, 0.f, 0.f, 0.f};
#pragma unroll 8
  for (int v = v0; v < v1; ++v) {
    float x = (l < 150) ? sd[(size_t)(v * 3 + c) * 150 + l] : vt[v * 3 + c];
#pragma unroll
    for (int j = 0; j < 5; ++j)
      acc[j] = fmaf(jreg[j * cV + v], x, acc[j]);
  }
#pragma unroll
  for (int j = 0; j < 5; ++j)
    atomicAdd(&JS[(j * 3 + c) * 151 + l], acc[j]);
}

// ---------------- k_batch: joints, rot mats, chain, A_rel, pose_feature, y_rot ----------------
// 256-thread blocks stage betas (coalesced) into LDS; 64 threads compute.
__global__ __launch_bounds__(256) void k_batch(
    const float* __restrict__ shp, const float* __restrict__ expr,
    const float* __restrict__ pose, const float* __restrict__ eyep,
    const float* __restrict__ JSg, float* __restrict__ Arel,
    float* __restrict__ pf, int* __restrict__ yrot) {
  __shared__ float js[2272];
  __shared__ float sb[64 * 153];            // stride 153: gcd(153%32=25,32)=1 -> conflict-free
  const int t = threadIdx.x;
  const int b0 = blockIdx.x * 64;
  for (int i = t; i < 2265; i += 256) js[i] = JSg[i];
  for (int e = t; e < 6400; e += 256) {
    int bl = e / 100, l = e - bl * 100;
    sb[bl * 153 + l] = shp[(size_t)(b0 + bl) * 100 + l];
  }
  for (int e = t; e < 3200; e += 256) {
    int bl = e / 50, l = e - bl * 50;
    sb[bl * 153 + 100 + l] = expr[(size_t)(b0 + bl) * 50 + l];
  }
  __syncthreads();
  if (t >= 64) return;
  int b = b0 + t;
  float jnt[5][3];
#pragma unroll
  for (int j = 0; j < 5; ++j)
#pragma unroll
    for (int c = 0; c < 3; ++c)
      jnt[j][c] = js[(j * 3 + c) * 151 + 150];
  for (int l = 0; l < 150; ++l) {
    float beta = sb[t * 153 + l];
#pragma unroll
    for (int j = 0; j < 5; ++j)
#pragma unroll
      for (int c = 0; c < 3; ++c)
        jnt[j][c] = fmaf(beta, js[(j * 3 + c) * 151 + l], jnt[j][c]);
  }
  float fp[5][3];
  fp[0][0] = pose[b * 6 + 0]; fp[0][1] = pose[b * 6 + 1]; fp[0][2] = pose[b * 6 + 2];
  fp[1][0] = 0.f; fp[1][1] = 0.f; fp[1][2] = 0.f;
  fp[2][0] = pose[b * 6 + 3]; fp[2][1] = pose[b * 6 + 4]; fp[2][2] = pose[b * 6 + 5];
  fp[3][0] = eyep[b * 6 + 0]; fp[3][1] = eyep[b * 6 + 1]; fp[3][2] = eyep[b * 6 + 2];
  fp[4][0] = eyep[b * 6 + 3]; fp[4][1] = eyep[b * 6 + 4]; fp[4][2] = eyep[b * 6 + 5];
  float R[5][9];
#pragma unroll
  for (int j = 0; j < 5; ++j) rodrigues9(fp[j][0], fp[j][1], fp[j][2], R[j]);
#pragma unroll
  for (int j = 1; j < 5; ++j)
#pragma unroll
    for (int r = 0; r < 9; ++r) {
      float id = (r == 0 || r == 4 || r == 8) ? 1.f : 0.f;
      pf[b * 36 + (j - 1) * 9 + r] = R[j][r] - id;
    }
  float rel[5][3];
#pragma unroll
  for (int c = 0; c < 3; ++c) {
    rel[0][c] = jnt[0][c];
    rel[1][c] = jnt[1][c] - jnt[0][c];
    rel[2][c] = jnt[2][c] - jnt[1][c];
    rel[3][c] = jnt[3][c] - jnt[1][c];
    rel[4][c] = jnt[4][c] - jnt[1][c];
  }
  float GR[5][9], Gt[5][3];
#pragma unroll
  for (int r = 0; r < 9; ++r) GR[0][r] = R[0][r];
#pragma unroll
  for (int c = 0; c < 3; ++c) Gt[0][c] = rel[0][c];
  const int par[5] = {0, 0, 1, 1, 1};
#pragma unroll
  for (int j = 1; j < 5; ++j) {
    int p = par[j];
#pragma unroll
    for (int r = 0; r < 3; ++r) {
#pragma unroll
      for (int cc = 0; cc < 3; ++cc)
        GR[j][r * 3 + cc] = GR[p][r * 3 + 0] * R[j][0 + cc] +
                            GR[p][r * 3 + 1] * R[j][3 + cc] +
                            GR[p][r * 3 + 2] * R[j][6 + cc];
      Gt[j][r] = Gt[p][r] + GR[p][r * 3 + 0] * rel[j][0] +
                            GR[p][r * 3 + 1] * rel[j][1] +
                            GR[p][r * 3 + 2] * rel[j][2];
    }
  }
#pragma unroll
  for (int j = 0; j < 5; ++j)
#pragma unroll
    for (int r = 0; r < 3; ++r) {
      float tj = Gt[j][r] - (GR[j][r * 3 + 0] * jnt[j][0] +
                             GR[j][r * 3 + 1] * jnt[j][1] +
                             GR[j][r * 3 + 2] * jnt[j][2]);
      Arel[b * 60 + j * 12 + r * 4 + 0] = GR[j][r * 3 + 0];
      Arel[b * 60 + j * 12 + r * 4 + 1] = GR[j][r * 3 + 1];
      Arel[b * 60 + j * 12 + r * 4 + 2] = GR[j][r * 3 + 2];
      Arel[b * 60 + j * 12 + r * 4 + 3] = tj;
    }
  float Ra[9], Rb[9];
  rodrigues9(fp[1][0], fp[1][1], fp[1][2], Ra);
  rodrigues9(fp[0][0], fp[0][1], fp[0][2], Rb);
  float r00 = Rb[0] * Ra[0] + Rb[1] * Ra[3] + Rb[2] * Ra[6];
  float r10 = Rb[3] * Ra[0] + Rb[4] * Ra[3] + Rb[5] * Ra[6];
  float r20 = Rb[6] * Ra[0] + Rb[7] * Ra[3] + Rb[8] * Ra[6];
  float sy = sqrtf(r00 * r00 + r10 * r10);
  float ydeg = atan2f(-r20, sy) * 57.29577951308232f;
  int y = (int)rintf(fminf(ydeg, 39.0f));
  if (y < 0) y = (y < -39) ? 78 : (39 - y);
  yrot[b] = y;
}

// ---------------- k_prep: build bf16 BTn[n][192] (sd part + zeros) and ATm[m][192] ----------------
#define QB ((size_t)cNPAD * 48)    // 723,456 quads for BTn
__global__ void k_prep(const float* __restrict__ sd, const float* __restrict__ shp,
                       const float* __restrict__ expr, const float* __restrict__ pfm,
                       unsigned int* __restrict__ btn_u2, unsigned int* __restrict__ atm_u2) {
  size_t idx = (size_t)blockIdx.x * 256 + threadIdx.x;
  unsigned short o[4];
  if (idx < QB) {
    int n = (int)(idx / 48), kq = (int)(idx - (size_t)n * 48);
#pragma unroll
    for (int j = 0; j < 4; ++j) {
      int k = kq * 4 + j;
      float v = (n < cV3 && k < 150) ? sd[(size_t)n * 150 + k] : 0.f;
      o[j] = f2bf(v);
    }
    btn_u2[idx * 2 + 0] = (unsigned int)o[0] | ((unsigned int)o[1] << 16);
    btn_u2[idx * 2 + 1] = (unsigned int)o[2] | ((unsigned int)o[3] << 16);
  } else {
    size_t r = idx - QB;            // 512*48 quads for ATm
    int m = (int)(r / 48), kq = (int)(r - (size_t)m * 48);
#pragma unroll
    for (int j = 0; j < 4; ++j) {
      int k = kq * 4 + j;
      float v;
      if (k < cS)            v = shp[m * cS + k];
      else if (k < 150)      v = expr[m * cE + (k - cS)];
      else if (k < 186)      v = pfm[m * 36 + (k - 150)];
      else                   v = 0.f;
      o[j] = f2bf(v);
    }
    atm_u2[r * 2 + 0] = (unsigned int)o[0] | ((unsigned int)o[1] << 16);
    atm_u2[r * 2 + 1] = (unsigned int)o[2] | ((unsigned int)o[3] << 16);
  }
}

// ---------------- k_pdT: transpose posedirs (36 x V3) into BTn[:,150:186) bf16 ----------------
__global__ void k_pdT(const float* __restrict__ pd, unsigned int* __restrict__ btn_u) {
  __shared__ unsigned short T[64 * 36];
  const int t = threadIdx.x;
  const int n0 = blockIdx.x * 64;
#pragma unroll
  for (int it = 0; it < 9; ++it) {
    int e = t + it * 256;            // e < 2304 = 36*64
    int kk = e >> 6, ln = e & 63;
    int n = n0 + ln;
    float v = (n < cV3) ? pd[(size_t)kk * cV3 + n] : 0.f;
    T[ln * 36 + kk] = f2bf(v);
  }
  __syncthreads();
  for (int e = t; e < 64 * 18; e += 256) {
    int ln = e / 18, d = e - ln * 18;
    int n = n0 + ln;
    if (n < cV3) {
      unsigned int w = (unsigned int)T[ln * 36 + 2 * d] |
                       ((unsigned int)T[ln * 36 + 2 * d + 1] << 16);
      btn_u[(size_t)n * 96 + 75 + d] = w;
    }
  }
}

// ---------------- k_main: MFMA bf16 GEMM (64b x 96n, K=192) + LBS epilogue ----------------
// B-only LDS (38.4 KB -> 4 blocks/CU); A frags + Arel direct from global (L2-hot).
__global__ __launch_bounds__(256, 4) void k_main(
    const unsigned short* __restrict__ BTn, const unsigned short* __restrict__ ATm,
    const float* __restrict__ Arel, const float* __restrict__ vtempl,
    const float* __restrict__ lbw, float* __restrict__ out) {
  __shared__ __align__(16) unsigned short smem[19200];   // Bs[96][200] bf16; reused as Pf[96][68] f32
  float* Pf = (float*)smem;

  const int t  = threadIdx.x;
  const int nb = blockIdx.x, mb = blockIdx.y;
  const int w = t >> 6, L = t & 63;
  const int wm = w >> 1, wn = w & 1;
  const int lr = L & 15, lq = L >> 4;

  // issue B tile loads (36,864 contiguous bytes, fully coalesced)
  const unsigned short* bsrc = BTn + (size_t)nb * 96 * 192;
  uint4 bst[9];
#pragma unroll
  for (int it = 0; it < 9; ++it)
    bst[it] = *(const uint4*)(bsrc + ((size_t)(t + it * 256)) * 8);

  // A fragments direct from global (ATm = 192 KB, L2-resident)
  const unsigned short* abase = ATm + ((size_t)mb * 64 + wm * 32 + lr) * 192 + lq * 8;
  short8 af[6][2];
#pragma unroll
  for (int ks = 0; ks < 6; ++ks)
#pragma unroll
    for (int mt = 0; mt < 2; ++mt)
      af[ks][mt] = *(const short8*)(abase + (size_t)mt * 16 * 192 + ks * 32);

  // store B tile to LDS (row stride 200: 2-way bank alias only)
#pragma unroll
  for (int it = 0; it < 9; ++it) {
    int e = t + it * 256;
    int row = e / 24, col = e - row * 24;
    *(uint4*)(smem + row * 200 + col * 8) = bst[it];
  }
  __syncthreads();

  f32x4 acc[2][3];
#pragma unroll
  for (int mt = 0; mt < 2; ++mt)
#pragma unroll
    for (int nt = 0; nt < 3; ++nt) acc[mt][nt] = (f32x4){0.f, 0.f, 0.f, 0.f};

#pragma unroll
  for (int ks = 0; ks < 6; ++ks) {
    const int ko = ks * 32 + lq * 8;
    short8 bf[3];
#pragma unroll
    for (int nt = 0; nt < 3; ++nt)
      bf[nt] = *(const short8*)(smem + (wn * 48 + nt * 16 + lr) * 200 + ko);
#pragma unroll
    for (int mt = 0; mt < 2; ++mt)
#pragma unroll
      for (int nt = 0; nt < 3; ++nt)
        acc[mt][nt] = __builtin_amdgcn_mfma_f32_16x16x32_bf16(af[ks][mt], bf[nt], acc[mt][nt], 0, 0, 0);
  }
  __syncthreads();   // all bf reads done; safe to overwrite LDS with Pf

  // acc -> LDS as P[n_loc][m_loc] (pad 68)
#pragma unroll
  for (int mt = 0; mt < 2; ++mt)
#pragma unroll
    for (int nt = 0; nt < 3; ++nt) {
      int m_base = wm * 32 + mt * 16 + lq * 4;
      int n_loc  = wn * 48 + nt * 16 + lr;
      *(f32x4*)(Pf + n_loc * 68 + m_base) = acc[mt][nt];
    }
  __syncthreads();

  // LBS epilogue: thread = (v_loc = t&31, bgrp = t>>5), loops 8 batches
  const int v_loc = t & 31, bgrp = t >> 5;
  const int v = nb * 32 + v_loc;
  float wj[5], vtl[3];
  const bool vok = (v < cV);
#pragma unroll
  for (int j = 0; j < 5; ++j) wj[j] = vok ? lbw[v * 5 + j] : 0.f;
#pragma unroll
  for (int c = 0; c < 3; ++c) vtl[c] = vok ? vtempl[v * 3 + c] : 0.f;

#pragma unroll
  for (int i = 0; i < 8; ++i) {
    const int b_loc = bgrp * 8 + i;
    const float* q = Arel + ((size_t)mb * 64 + b_loc) * 60;   // uniform per half-wave -> 1 fetch
    float px = Pf[(v_loc * 3 + 0) * 68 + b_loc] + vtl[0];
    float py = Pf[(v_loc * 3 + 1) * 68 + b_loc] + vtl[1];
    float pz = Pf[(v_loc * 3 + 2) * 68 + b_loc] + vtl[2];
    float o0 = 0.f, o1 = 0.f, o2 = 0.f;
#pragma unroll
    for (int j = 0; j < 5; ++j) {
      f32x4 q0 = *(const f32x4*)(q + j * 12);
      f32x4 q1 = *(const f32x4*)(q + j * 12 + 4);
      f32x4 q2 = *(const f32x4*)(q + j * 12 + 8);
      float s0 = q0.x * px + q0.y * py + q0.z * pz + q0.w;
      float s1 = q1.x * px + q1.y * py + q1.z * pz + q1.w;
      float s2 = q2.x * px + q2.y * py + q2.z * pz + q2.w;
      o0 = fmaf(wj[j], s0, o0);
      o1 = fmaf(wj[j], s1, o1);
      o2 = fmaf(wj[j], s2, o2);
    }
    if (vok) {
      const int b = mb * 64 + b_loc;
      size_t off = ((size_t)b * cV + v) * 3;
      out[off + 0] = o0;
      out[off + 1] = o1;
      out[off + 2] = o2;
    }
  }
}

// ---------------- k_lmk: barycentric landmark gather, 1 thread per (b, l, which) ----------------
__global__ void k_lmk(const float* __restrict__ verts, const int* __restrict__ faces,
                      const int* __restrict__ lmkf, const float* __restrict__ lmkb,
                      const int* __restrict__ dynf, const float* __restrict__ dynb,
                      const int* __restrict__ fullf, const float* __restrict__ fullb,
                      const int* __restrict__ yrot, float* __restrict__ out) {
  int id = blockIdx.x * 256 + threadIdx.x;
  if (id >= cB * cLF * 2) return;
  int sel = id & 1;
  int r = id >> 1;
  int b = r / cLF, l = r - b * cLF;
  const float* vb = verts + (size_t)b * cV * 3;
  int f; float w0, w1, w2; size_t o;
  if (sel == 0) {
    if (l < cLD) {
      int yb = yrot[b];
      f = dynf[yb * cLD + l];
      const float* bp = dynb + ((size_t)yb * cLD + l) * 3;
      w0 = bp[0]; w1 = bp[1]; w2 = bp[2];
    } else {
      f = lmkf[l - cLD];
      const float* bp = lmkb + (size_t)(l - cLD) * 3;
      w0 = bp[0]; w1 = bp[1]; w2 = bp[2];
    }
    o = OUT_V + ((size_t)b * cLF + l) * 3;
  } else {
    f = fullf[l];
    const float* bp = fullb + (size_t)l * 3;
    w0 = bp[0]; w1 = bp[1]; w2 = bp[2];
    o = OUT_V + OUT_L + ((size_t)b * cLF + l) * 3;
  }
  int i0 = faces[f * 3 + 0] * 3, i1 = faces[f * 3 + 1] * 3, i2 = faces[f * 3 + 2] * 3;
  out[o + 0] = w0 * vb[i0 + 0] + w1 * vb[i1 + 0] + w2 * vb[i2 + 0];
  out[o + 1] = w0 * vb[i0 + 1] + w1 * vb[i1 + 1] + w2 * vb[i2 + 1];
  out[o + 2] = w0 * vb[i0 + 2] + w1 * vb[i1 + 2] + w2 * vb[i2 + 2];
}

// ---------------- launch ----------------
extern "C" void kernel_launch(void* const* d_in, const int* in_sizes, int n_in,
                              void* d_out, int out_size, void* d_ws, size_t ws_size,
                              hipStream_t stream) {
  (void)in_sizes; (void)n_in; (void)out_size; (void)ws_size;
  const float* shp  = (const float*)d_in[0];
  const float* expr = (const float*)d_in[1];
  const float* pose = (const float*)d_in[2];
  const float* eyep = (const float*)d_in[3];
  const float* vt   = (const float*)d_in[4];
  const float* sd   = (const float*)d_in[5];
  const float* pd   = (const float*)d_in[6];
  const float* jreg = (const float*)d_in[7];
  const float* lbw  = (const float*)d_in[8];
  const int*   fcs  = (const int*)d_in[9];
  const int*   lmkf = (const int*)d_in[10];
  const float* lmkb = (const float*)d_in[11];
  const int*   dynf = (const int*)d_in[12];
  const float* dynb = (const float*)d_in[13];
  const int*   fullf= (const int*)d_in[14];
  const float* fullb= (const float*)d_in[15];
  float* out = (float*)d_out;
  float* ws  = (float*)d_ws;

  unsigned short* BTn = (unsigned short*)(ws + WS_BTN);
  unsigned short* ATm = (unsigned short*)(ws + WS_ATM);
  float* JS   = ws + WS_JS;
  float* Arel = ws + WS_AREL;
  float* pf   = ws + WS_PF;
  int*   yrot = (int*)(ws + WS_YROT);

  hipMemsetAsync(JS, 0, 2272 * sizeof(float), stream);
  k_js<<<157, 512, 0, stream>>>(jreg, sd, vt, JS);
  k_batch<<<8, 256, 0, stream>>>(shp, expr, pose, eyep, JS, Arel, pf, yrot);
  k_prep<<<2922, 256, 0, stream>>>(sd, shp, expr, pf,
                                   (unsigned int*)BTn, (unsigned int*)ATm);
  k_pdT<<<236, 256, 0, stream>>>(pd, (unsigned int*)BTn);
  k_main<<<dim3(157, 8), 256, 0, stream>>>(BTn, ATm, Arel, vt, lbw, out);
  k_lmk<<<272, 256, 0, stream>>>(out, fcs, lmkf, lmkb, dynf, dynb, fullf, fullb, yrot, out);
}

// Round 4
// 186.476 us; speedup vs baseline: 1.1281x; 1.1281x over previous
//
#include <hip/hip_runtime.h>
#include <cstddef>
#include <cstdint>

// ---------------- problem constants ----------------
#define cB   512
#define cV   5023
#define cS   100
#define cE   50
#define cJ   5
#define cLD  17
#define cLF  68

#define cV3    15069       // V*3
#define cNPAD  15072       // 157*96 padded N (rows of BTn)
#define cKPAD  192         // K padded (100+50+36 -> 192)

#define OUT_V  ((size_t)cB * cV * 3)
#define OUT_L  ((size_t)cB * cLF * 3)

// ws layout (float offsets; bf16 buffers are ushort-packed, 2 per float)
// JSpart ALIASES the BTn region: k_js/k_jsred run before k_prep writes BTn.
#define WS_BTN   ((size_t)0)                            // 15072*96 dwords (bf16 x2)
#define WS_ATM   (WS_BTN + (size_t)cNPAD * 96)          // 512*96 dwords
#define WS_JS2   (WS_ATM + (size_t)cB * 96)             // 151*16 floats
#define WS_AREL  (WS_JS2 + 2432)                        // 512*60
#define WS_PF    (WS_AREL + (size_t)cB * 60)            // 512*36
#define WS_YROT  (WS_PF + (size_t)cB * 36)              // 512 ints

typedef __attribute__((ext_vector_type(8))) short short8;
typedef __attribute__((ext_vector_type(4))) float f32x4;

// fp32 -> bf16 round-to-nearest-even
__device__ __forceinline__ unsigned short f2bf(float x) {
  unsigned int u = __float_as_uint(x);
  u = (u + 0x7fffu + ((u >> 16) & 1u)) >> 16;
  return (unsigned short)u;
}

// ---------------- rodrigues (matches jax reference in fp32) ----------------
__device__ __forceinline__ void rodrigues9(float rx, float ry, float rz, float* R) {
  float a0 = rx + 1e-8f, a1 = ry + 1e-8f, a2 = rz + 1e-8f;
  float angle = sqrtf(a0 * a0 + a1 * a1 + a2 * a2);
  float inv = 1.0f / angle;
  float x = rx * inv, y = ry * inv, z = rz * inv;
  float s = sinf(angle), c = cosf(angle);
  float t = 1.0f - c;
  float xy = x * y, xz = x * z, yz = y * z;
  R[0] = 1.0f - t * (y * y + z * z);
  R[1] = -s * z + t * xy;
  R[2] =  s * y + t * xz;
  R[3] =  s * z + t * xy;
  R[4] = 1.0f - t * (x * x + z * z);
  R[5] = -s * x + t * yz;
  R[6] = -s * y + t * xz;
  R[7] =  s * x + t * yz;
  R[8] = 1.0f - t * (x * x + y * y);
}

// ---------------- k_js: per-block partial JS sums (NO atomics) ----------------
// JSpart[p][2272]: partial over v-range p of sum_v jreg[j,v]*sd[v,c,l] (l==150 -> vt).
__global__ void k_js(const float* __restrict__ jreg, const float* __restrict__ sd,
                     const float* __restrict__ vt, float* __restrict__ JSpart) {
  int t = threadIdx.x;
  if (t >= 453) return;
  int c = t / 151, l = t - c * 151;
  int v0 = blockIdx.x * 32;
  int v1 = v0 + 32; if (v1 > cV) v1 = cV;
  float acc[5] = {0.f, 0.f, 0.f, 0.f, 0.f};
#pragma unroll 8
  for (int v = v0; v < v1; ++v) {
    float x = (l < 150) ? sd[(size_t)(v * 3 + c) * 150 + l] : vt[v * 3 + c];
#pragma unroll
    for (int j = 0; j < 5; ++j)
      acc[j] = fmaf(jreg[j * cV + v], x, acc[j]);
  }
#pragma unroll
  for (int j = 0; j < 5; ++j)
    JSpart[(size_t)blockIdx.x * 2272 + (j * 3 + c) * 151 + l] = acc[j];
}

// ---------------- k_jsred: reduce 157 partials -> JS2[l][16] (jc-major float4 layout) ----
__global__ void k_jsred(const float* __restrict__ JSpart, float* __restrict__ JS2) {
  int e = blockIdx.x * 256 + threadIdx.x;
  if (e >= 2265) return;
  float s = 0.f;
#pragma unroll 8
  for (int p = 0; p < 157; ++p)
    s += JSpart[(size_t)p * 2272 + e];
  int jc = e / 151, l = e - jc * 151;
  JS2[l * 16 + jc] = s;
}

// ---------------- k_batch: joints, rot mats, chain, A_rel, pose_feature, y_rot ----------------
__global__ __launch_bounds__(256) void k_batch(
    const float* __restrict__ shp, const float* __restrict__ expr,
    const float* __restrict__ pose, const float* __restrict__ eyep,
    const float* __restrict__ JS2g, float* __restrict__ Arel,
    float* __restrict__ pf, int* __restrict__ yrot) {
  __shared__ float js2[151 * 16];
  __shared__ float sb[64 * 153];            // stride 153: odd -> 2-way alias only (free)
  const int t = threadIdx.x;
  const int b0 = blockIdx.x * 64;
  for (int i = t; i < 151 * 16; i += 256) js2[i] = JS2g[i];
  for (int e = t; e < 6400; e += 256) {
    int bl = e / 100, l = e - bl * 100;
    sb[bl * 153 + l] = shp[(size_t)(b0 + bl) * 100 + l];
  }
  for (int e = t; e < 3200; e += 256) {
    int bl = e / 50, l = e - bl * 50;
    sb[bl * 153 + 100 + l] = expr[(size_t)(b0 + bl) * 50 + l];
  }
  __syncthreads();
  if (t >= 64) return;
  int b = b0 + t;
  float jnt[5][3];
  {
    const f32x4* J4 = (const f32x4*)(js2 + 150 * 16);
    f32x4 A = J4[0], Bq = J4[1], Cq = J4[2], Dq = J4[3];
    jnt[0][0] = A.x;  jnt[0][1] = A.y;  jnt[0][2] = A.z;
    jnt[1][0] = A.w;  jnt[1][1] = Bq.x; jnt[1][2] = Bq.y;
    jnt[2][0] = Bq.z; jnt[2][1] = Bq.w; jnt[2][2] = Cq.x;
    jnt[3][0] = Cq.y; jnt[3][1] = Cq.z; jnt[3][2] = Cq.w;
    jnt[4][0] = Dq.x; jnt[4][1] = Dq.y; jnt[4][2] = Dq.z;
  }
  for (int l = 0; l < 150; ++l) {
    const f32x4* J4 = (const f32x4*)(js2 + l * 16);   // broadcast reads (free)
    f32x4 A = J4[0], Bq = J4[1], Cq = J4[2], Dq = J4[3];
    float beta = sb[t * 153 + l];
    jnt[0][0] = fmaf(beta, A.x,  jnt[0][0]);
    jnt[0][1] = fmaf(beta, A.y,  jnt[0][1]);
    jnt[0][2] = fmaf(beta, A.z,  jnt[0][2]);
    jnt[1][0] = fmaf(beta, A.w,  jnt[1][0]);
    jnt[1][1] = fmaf(beta, Bq.x, jnt[1][1]);
    jnt[1][2] = fmaf(beta, Bq.y, jnt[1][2]);
    jnt[2][0] = fmaf(beta, Bq.z, jnt[2][0]);
    jnt[2][1] = fmaf(beta, Bq.w, jnt[2][1]);
    jnt[2][2] = fmaf(beta, Cq.x, jnt[2][2]);
    jnt[3][0] = fmaf(beta, Cq.y, jnt[3][0]);
    jnt[3][1] = fmaf(beta, Cq.z, jnt[3][1]);
    jnt[3][2] = fmaf(beta, Cq.w, jnt[3][2]);
    jnt[4][0] = fmaf(beta, Dq.x, jnt[4][0]);
    jnt[4][1] = fmaf(beta, Dq.y, jnt[4][1]);
    jnt[4][2] = fmaf(beta, Dq.z, jnt[4][2]);
  }
  float fp[5][3];
  fp[0][0] = pose[b * 6 + 0]; fp[0][1] = pose[b * 6 + 1]; fp[0][2] = pose[b * 6 + 2];
  fp[1][0] = 0.f; fp[1][1] = 0.f; fp[1][2] = 0.f;
  fp[2][0] = pose[b * 6 + 3]; fp[2][1] = pose[b * 6 + 4]; fp[2][2] = pose[b * 6 + 5];
  fp[3][0] = eyep[b * 6 + 0]; fp[3][1] = eyep[b * 6 + 1]; fp[3][2] = eyep[b * 6 + 2];
  fp[4][0] = eyep[b * 6 + 3]; fp[4][1] = eyep[b * 6 + 4]; fp[4][2] = eyep[b * 6 + 5];
  float R[5][9];
#pragma unroll
  for (int j = 0; j < 5; ++j) rodrigues9(fp[j][0], fp[j][1], fp[j][2], R[j]);
#pragma unroll
  for (int j = 1; j < 5; ++j)
#pragma unroll
    for (int r = 0; r < 9; ++r) {
      float id = (r == 0 || r == 4 || r == 8) ? 1.f : 0.f;
      pf[b * 36 + (j - 1) * 9 + r] = R[j][r] - id;
    }
  float rel[5][3];
#pragma unroll
  for (int c = 0; c < 3; ++c) {
    rel[0][c] = jnt[0][c];
    rel[1][c] = jnt[1][c] - jnt[0][c];
    rel[2][c] = jnt[2][c] - jnt[1][c];
    rel[3][c] = jnt[3][c] - jnt[1][c];
    rel[4][c] = jnt[4][c] - jnt[1][c];
  }
  float GR[5][9], Gt[5][3];
#pragma unroll
  for (int r = 0; r < 9; ++r) GR[0][r] = R[0][r];
#pragma unroll
  for (int c = 0; c < 3; ++c) Gt[0][c] = rel[0][c];
  const int par[5] = {0, 0, 1, 1, 1};
#pragma unroll
  for (int j = 1; j < 5; ++j) {
    int p = par[j];
#pragma unroll
    for (int r = 0; r < 3; ++r) {
#pragma unroll
      for (int cc = 0; cc < 3; ++cc)
        GR[j][r * 3 + cc] = GR[p][r * 3 + 0] * R[j][0 + cc] +
                            GR[p][r * 3 + 1] * R[j][3 + cc] +
                            GR[p][r * 3 + 2] * R[j][6 + cc];
      Gt[j][r] = Gt[p][r] + GR[p][r * 3 + 0] * rel[j][0] +
                            GR[p][r * 3 + 1] * rel[j][1] +
                            GR[p][r * 3 + 2] * rel[j][2];
    }
  }
#pragma unroll
  for (int j = 0; j < 5; ++j)
#pragma unroll
    for (int r = 0; r < 3; ++r) {
      float tj = Gt[j][r] - (GR[j][r * 3 + 0] * jnt[j][0] +
                             GR[j][r * 3 + 1] * jnt[j][1] +
                             GR[j][r * 3 + 2] * jnt[j][2]);
      Arel[b * 60 + j * 12 + r * 4 + 0] = GR[j][r * 3 + 0];
      Arel[b * 60 + j * 12 + r * 4 + 1] = GR[j][r * 3 + 1];
      Arel[b * 60 + j * 12 + r * 4 + 2] = GR[j][r * 3 + 2];
      Arel[b * 60 + j * 12 + r * 4 + 3] = tj;
    }
  float Ra[9], Rb[9];
  rodrigues9(fp[1][0], fp[1][1], fp[1][2], Ra);
  rodrigues9(fp[0][0], fp[0][1], fp[0][2], Rb);
  float r00 = Rb[0] * Ra[0] + Rb[1] * Ra[3] + Rb[2] * Ra[6];
  float r10 = Rb[3] * Ra[0] + Rb[4] * Ra[3] + Rb[5] * Ra[6];
  float r20 = Rb[6] * Ra[0] + Rb[7] * Ra[3] + Rb[8] * Ra[6];
  float sy = sqrtf(r00 * r00 + r10 * r10);
  float ydeg = atan2f(-r20, sy) * 57.29577951308232f;
  int y = (int)rintf(fminf(ydeg, 39.0f));
  if (y < 0) y = (y < -39) ? 78 : (39 - y);
  yrot[b] = y;
}

// ---------------- k_prep: build bf16 BTn[n][192] (sd part + zeros) and ATm[m][192] ----------------
#define QB ((size_t)cNPAD * 48)    // 723,456 quads for BTn
__global__ void k_prep(const float* __restrict__ sd, const float* __restrict__ shp,
                       const float* __restrict__ expr, const float* __restrict__ pfm,
                       unsigned int* __restrict__ btn_u2, unsigned int* __restrict__ atm_u2) {
  size_t idx = (size_t)blockIdx.x * 256 + threadIdx.x;
  unsigned short o[4];
  if (idx < QB) {
    int n = (int)(idx / 48), kq = (int)(idx - (size_t)n * 48);
#pragma unroll
    for (int j = 0; j < 4; ++j) {
      int k = kq * 4 + j;
      float v = (n < cV3 && k < 150) ? sd[(size_t)n * 150 + k] : 0.f;
      o[j] = f2bf(v);
    }
    btn_u2[idx * 2 + 0] = (unsigned int)o[0] | ((unsigned int)o[1] << 16);
    btn_u2[idx * 2 + 1] = (unsigned int)o[2] | ((unsigned int)o[3] << 16);
  } else {
    size_t r = idx - QB;            // 512*48 quads for ATm
    int m = (int)(r / 48), kq = (int)(r - (size_t)m * 48);
#pragma unroll
    for (int j = 0; j < 4; ++j) {
      int k = kq * 4 + j;
      float v;
      if (k < cS)            v = shp[m * cS + k];
      else if (k < 150)      v = expr[m * cE + (k - cS)];
      else if (k < 186)      v = pfm[m * 36 + (k - 150)];
      else                   v = 0.f;
      o[j] = f2bf(v);
    }
    atm_u2[r * 2 + 0] = (unsigned int)o[0] | ((unsigned int)o[1] << 16);
    atm_u2[r * 2 + 1] = (unsigned int)o[2] | ((unsigned int)o[3] << 16);
  }
}

// ---------------- k_pdT: transpose posedirs (36 x V3) into BTn[:,150:186) bf16 ----------------
__global__ void k_pdT(const float* __restrict__ pd, unsigned int* __restrict__ btn_u) {
  __shared__ unsigned short T[64 * 36];
  const int t = threadIdx.x;
  const int n0 = blockIdx.x * 64;
#pragma unroll
  for (int it = 0; it < 9; ++it) {
    int e = t + it * 256;            // e < 2304 = 36*64
    int kk = e >> 6, ln = e & 63;
    int n = n0 + ln;
    float v = (n < cV3) ? pd[(size_t)kk * cV3 + n] : 0.f;
    T[ln * 36 + kk] = f2bf(v);
  }
  __syncthreads();
  for (int e = t; e < 64 * 18; e += 256) {
    int ln = e / 18, d = e - ln * 18;
    int n = n0 + ln;
    if (n < cV3) {
      unsigned int w = (unsigned int)T[ln * 36 + 2 * d] |
                       ((unsigned int)T[ln * 36 + 2 * d + 1] << 16);
      btn_u[(size_t)n * 96 + 75 + d] = w;
    }
  }
}

// ---------------- k_main: MFMA bf16 GEMM (64b x 96n, K=192) + LBS epilogue ----------------
// B in LDS (38.4 KB -> 4 blocks/CU); A frags loaded per-ks from L2-hot ATm (low VGPR, no spill).
// 1D grid with XCD swizzle: same-nb blocks land on the same XCD for B-tile L2 reuse.
__global__ __launch_bounds__(256) void k_main(
    const unsigned short* __restrict__ BTn, const unsigned short* __restrict__ ATm,
    const float* __restrict__ Arel, const float* __restrict__ vtempl,
    const float* __restrict__ lbw, float* __restrict__ out) {
  __shared__ __align__(16) unsigned short smem[19200];   // Bs[96][200] bf16; reused as Pf[96][68] f32
  float* Pf = (float*)smem;

  // swizzle: bid = 64*nbh + 8*m + r ; nb = 8*nbh + r (same nb -> bids stride 8 -> same XCD)
  const int bid = blockIdx.x;
  const int r8 = bid & 7, q = bid >> 3;
  const int mb = q & 7, nbh = q >> 3;
  const int nb = (nbh << 3) | r8;
  if (nb >= 157) return;

  const int t = threadIdx.x;
  const int w = t >> 6, L = t & 63;
  const int wm = w >> 1, wn = w & 1;
  const int lr = L & 15, lq = L >> 4;

  // stage B tile (36,864 contiguous bytes, fully coalesced) via regs -> LDS pad 200
  const unsigned short* bsrc = BTn + (size_t)nb * 96 * 192;
  uint4 bst[9];
#pragma unroll
  for (int it = 0; it < 9; ++it)
    bst[it] = *(const uint4*)(bsrc + ((size_t)(t + it * 256)) * 8);
#pragma unroll
  for (int it = 0; it < 9; ++it) {
    int e = t + it * 256;
    int row = e / 24, col = e - row * 24;
    *(uint4*)(smem + row * 200 + col * 8) = bst[it];
  }
  __syncthreads();

  f32x4 acc[2][3];
#pragma unroll
  for (int mt = 0; mt < 2; ++mt)
#pragma unroll
    for (int nt = 0; nt < 3; ++nt) acc[mt][nt] = (f32x4){0.f, 0.f, 0.f, 0.f};

  const unsigned short* abase = ATm + ((size_t)mb * 64 + wm * 32 + lr) * 192 + lq * 8;
#pragma unroll
  for (int ks = 0; ks < 6; ++ks) {
    short8 af0 = *(const short8*)(abase + ks * 32);            // L2-hot (ATm = 192 KB)
    short8 af1 = *(const short8*)(abase + 16 * 192 + ks * 32);
    const int ko = ks * 32 + lq * 8;
    short8 bf[3];
#pragma unroll
    for (int nt = 0; nt < 3; ++nt)
      bf[nt] = *(const short8*)(smem + (wn * 48 + nt * 16 + lr) * 200 + ko);
#pragma unroll
    for (int nt = 0; nt < 3; ++nt) {
      acc[0][nt] = __builtin_amdgcn_mfma_f32_16x16x32_bf16(af0, bf[nt], acc[0][nt], 0, 0, 0);
      acc[1][nt] = __builtin_amdgcn_mfma_f32_16x16x32_bf16(af1, bf[nt], acc[1][nt], 0, 0, 0);
    }
  }
  __syncthreads();   // all bf reads done; safe to overwrite LDS with Pf

  // acc -> LDS as P[n_loc][m_loc] (pad 68)
#pragma unroll
  for (int mt = 0; mt < 2; ++mt)
#pragma unroll
    for (int nt = 0; nt < 3; ++nt) {
      int m_base = wm * 32 + mt * 16 + lq * 4;
      int n_loc  = wn * 48 + nt * 16 + lr;
      *(f32x4*)(Pf + n_loc * 68 + m_base) = acc[mt][nt];
    }
  __syncthreads();

  // LBS epilogue: thread = (v_loc = t&31, bgrp = t>>5), loops 8 batches
  const int v_loc = t & 31, bgrp = t >> 5;
  const int v = nb * 32 + v_loc;
  float wj[5], vtl[3];
  const bool vok = (v < cV);
#pragma unroll
  for (int j = 0; j < 5; ++j) wj[j] = vok ? lbw[v * 5 + j] : 0.f;
#pragma unroll
  for (int c = 0; c < 3; ++c) vtl[c] = vok ? vtempl[v * 3 + c] : 0.f;

#pragma unroll
  for (int i = 0; i < 8; ++i) {
    const int b_loc = bgrp * 8 + i;
    const float* qb = Arel + ((size_t)mb * 64 + b_loc) * 60;   // 2 uniform addrs per wave, L2-hot
    float px = Pf[(v_loc * 3 + 0) * 68 + b_loc] + vtl[0];
    float py = Pf[(v_loc * 3 + 1) * 68 + b_loc] + vtl[1];
    float pz = Pf[(v_loc * 3 + 2) * 68 + b_loc] + vtl[2];
    float o0 = 0.f, o1 = 0.f, o2 = 0.f;
#pragma unroll
    for (int j = 0; j < 5; ++j) {
      f32x4 q0 = *(const f32x4*)(qb + j * 12);
      f32x4 q1 = *(const f32x4*)(qb + j * 12 + 4);
      f32x4 q2 = *(const f32x4*)(qb + j * 12 + 8);
      float s0 = q0.x * px + q0.y * py + q0.z * pz + q0.w;
      float s1 = q1.x * px + q1.y * py + q1.z * pz + q1.w;
      float s2 = q2.x * px + q2.y * py + q2.z * pz + q2.w;
      o0 = fmaf(wj[j], s0, o0);
      o1 = fmaf(wj[j], s1, o1);
      o2 = fmaf(wj[j], s2, o2);
    }
    if (vok) {
      const int b = mb * 64 + b_loc;
      size_t off = ((size_t)b * cV + v) * 3;
      out[off + 0] = o0;
      out[off + 1] = o1;
      out[off + 2] = o2;
    }
  }
}

// ---------------- k_lmk: barycentric landmark gather, 1 thread per (b, l, which) ----------------
__global__ void k_lmk(const float* __restrict__ verts, const int* __restrict__ faces,
                      const int* __restrict__ lmkf, const float* __restrict__ lmkb,
                      const int* __restrict__ dynf, const float* __restrict__ dynb,
                      const int* __restrict__ fullf, const float* __restrict__ fullb,
                      const int* __restrict__ yrot, float* __restrict__ out) {
  int id = blockIdx.x * 256 + threadIdx.x;
  if (id >= cB * cLF * 2) return;
  int sel = id & 1;
  int r = id >> 1;
  int b = r / cLF, l = r - b * cLF;
  const float* vb = verts + (size_t)b * cV * 3;
  int f; float w0, w1, w2; size_t o;
  if (sel == 0) {
    if (l < cLD) {
      int yb = yrot[b];
      f = dynf[yb * cLD + l];
      const float* bp = dynb + ((size_t)yb * cLD + l) * 3;
      w0 = bp[0]; w1 = bp[1]; w2 = bp[2];
    } else {
      f = lmkf[l - cLD];
      const float* bp = lmkb + (size_t)(l - cLD) * 3;
      w0 = bp[0]; w1 = bp[1]; w2 = bp[2];
    }
    o = OUT_V + ((size_t)b * cLF + l) * 3;
  } else {
    f = fullf[l];
    const float* bp = fullb + (size_t)l * 3;
    w0 = bp[0]; w1 = bp[1]; w2 = bp[2];
    o = OUT_V + OUT_L + ((size_t)b * cLF + l) * 3;
  }
  int i0 = faces[f * 3 + 0] * 3, i1 = faces[f * 3 + 1] * 3, i2 = faces[f * 3 + 2] * 3;
  out[o + 0] = w0 * vb[i0 + 0] + w1 * vb[i1 + 0] + w2 * vb[i2 + 0];
  out[o + 1] = w0 * vb[i0 + 1] + w1 * vb[i1 + 1] + w2 * vb[i2 + 1];
  out[o + 2] = w0 * vb[i0 + 2] + w1 * vb[i1 + 2] + w2 * vb[i2 + 2];
}

// ---------------- launch ----------------
extern "C" void kernel_launch(void* const* d_in, const int* in_sizes, int n_in,
                              void* d_out, int out_size, void* d_ws, size_t ws_size,
                              hipStream_t stream) {
  (void)in_sizes; (void)n_in; (void)out_size; (void)ws_size;
  const float* shp  = (const float*)d_in[0];
  const float* expr = (const float*)d_in[1];
  const float* pose = (const float*)d_in[2];
  const float* eyep = (const float*)d_in[3];
  const float* vt   = (const float*)d_in[4];
  const float* sd   = (const float*)d_in[5];
  const float* pd   = (const float*)d_in[6];
  const float* jreg = (const float*)d_in[7];
  const float* lbw  = (const float*)d_in[8];
  const int*   fcs  = (const int*)d_in[9];
  const int*   lmkf = (const int*)d_in[10];
  const float* lmkb = (const float*)d_in[11];
  const int*   dynf = (const int*)d_in[12];
  const float* dynb = (const float*)d_in[13];
  const int*   fullf= (const int*)d_in[14];
  const float* fullb= (const float*)d_in[15];
  float* out = (float*)d_out;
  float* ws  = (float*)d_ws;

  unsigned short* BTn = (unsigned short*)(ws + WS_BTN);
  unsigned short* ATm = (unsigned short*)(ws + WS_ATM);
  float* JSpart = ws + WS_BTN;              // aliases BTn region (consumed before k_prep)
  float* JS2  = ws + WS_JS2;
  float* Arel = ws + WS_AREL;
  float* pf   = ws + WS_PF;
  int*   yrot = (int*)(ws + WS_YROT);

  k_js<<<157, 512, 0, stream>>>(jreg, sd, vt, JSpart);
  k_jsred<<<9, 256, 0, stream>>>(JSpart, JS2);
  k_batch<<<8, 256, 0, stream>>>(shp, expr, pose, eyep, JS2, Arel, pf, yrot);
  k_prep<<<2922, 256, 0, stream>>>(sd, shp, expr, pf,
                                   (unsigned int*)BTn, (unsigned int*)ATm);
  k_pdT<<<236, 256, 0, stream>>>(pd, (unsigned int*)BTn);
  k_main<<<1280, 256, 0, stream>>>(BTn, ATm, Arel, vt, lbw, out);
  k_lmk<<<272, 256, 0, stream>>>(out, fcs, lmkf, lmkb, dynf, dynb, fullf, fullb, yrot, out);
}